// Round 1
// baseline (335.891 us; speedup 1.0000x reference)
//
#include <hip/hip_runtime.h>
#include <math.h>

#define VOCAB   50265
#define D       768
#define N_NEW   200
#define N_NODES 199
#define N_EDGES 1024
#define LEAKY   0.2f

// ---------------- Kernel 1: h = feats @ W, plus s[i]=h[i].a_src, d[i]=h[i].a_dst
// feats = new_emb rows 1..199. 8 rows per block, 256 threads, 3 cols/thread.
#define ROWS_PB 8

__global__ __launch_bounds__(256) void gemm_sd_kernel(
    const float* __restrict__ new_emb, const float* __restrict__ W,
    const float* __restrict__ a_src, const float* __restrict__ a_dst,
    float* __restrict__ h, float* __restrict__ sv, float* __restrict__ dv)
{
    __shared__ float fts[ROWS_PB][D];        // 24 KB
    __shared__ float redS[4], redD[4];
    const int tid  = threadIdx.x;
    const int row0 = blockIdx.x * ROWS_PB;
    const int nrows = min(ROWS_PB, N_NODES - row0);

    for (int r = 0; r < nrows; ++r)
        for (int k = tid; k < D; k += 256)
            fts[r][k] = new_emb[(size_t)(1 + row0 + r) * D + k];
    for (int r = nrows; r < ROWS_PB; ++r)
        for (int k = tid; k < D; k += 256)
            fts[r][k] = 0.f;
    __syncthreads();

    float acc[ROWS_PB][3];
    for (int r = 0; r < ROWS_PB; ++r)
        for (int j = 0; j < 3; ++j) acc[r][j] = 0.f;

    for (int k = 0; k < D; ++k) {
        float w0 = W[(size_t)k * D + tid];
        float w1 = W[(size_t)k * D + tid + 256];
        float w2 = W[(size_t)k * D + tid + 512];
        #pragma unroll
        for (int r = 0; r < ROWS_PB; ++r) {
            float f = fts[r][k];
            acc[r][0] = fmaf(f, w0, acc[r][0]);
            acc[r][1] = fmaf(f, w1, acc[r][1]);
            acc[r][2] = fmaf(f, w2, acc[r][2]);
        }
    }

    const float as0 = a_src[tid], as1 = a_src[tid + 256], as2 = a_src[tid + 512];
    const float ad0 = a_dst[tid], ad1 = a_dst[tid + 256], ad2 = a_dst[tid + 512];

    for (int r = 0; r < nrows; ++r) {
        const int row = row0 + r;
        h[(size_t)row * D + tid]       = acc[r][0];
        h[(size_t)row * D + tid + 256] = acc[r][1];
        h[(size_t)row * D + tid + 512] = acc[r][2];

        float ps = acc[r][0] * as0 + acc[r][1] * as1 + acc[r][2] * as2;
        float pd = acc[r][0] * ad0 + acc[r][1] * ad1 + acc[r][2] * ad2;
        #pragma unroll
        for (int off = 32; off; off >>= 1) {
            ps += __shfl_down(ps, off, 64);
            pd += __shfl_down(pd, off, 64);
        }
        if ((tid & 63) == 0) { redS[tid >> 6] = ps; redD[tid >> 6] = pd; }
        __syncthreads();
        if (tid == 0) {
            sv[row] = redS[0] + redS[1] + redS[2] + redS[3];
            dv[row] = redD[0] + redD[1] + redD[2] + redD[3];
        }
        __syncthreads();
    }
}

// ---------------- Kernel 2: per-edge softmax weights (single block)
__global__ __launch_bounds__(256) void softmax_kernel(
    const int* __restrict__ edge_index, const float* __restrict__ sv,
    const float* __restrict__ dv, float* __restrict__ alpha)
{
    __shared__ float e[N_EDGES];
    __shared__ int   sdst[N_EDGES];
    __shared__ float m[N_NODES];
    __shared__ float denom[N_NODES];
    const int tid = threadIdx.x;

    for (int k = tid; k < N_EDGES; k += 256) {
        int s = edge_index[k];
        int d = edge_index[N_EDGES + k];
        sdst[k] = d;
        float ev = sv[s] + dv[d];
        e[k] = ev > 0.f ? ev : LEAKY * ev;
    }
    __syncthreads();

    for (int n = tid; n < N_NODES; n += 256) {
        float mx = -INFINITY;
        for (int k = 0; k < N_EDGES; ++k)
            if (sdst[k] == n) mx = fmaxf(mx, e[k]);
        float dn = 0.f;
        for (int k = 0; k < N_EDGES; ++k)
            if (sdst[k] == n) dn += expf(e[k] - mx);
        m[n] = mx;
        denom[n] = dn;
    }
    __syncthreads();

    for (int k = tid; k < N_EDGES; k += 256) {
        int d = sdst[k];
        alpha[k] = expf(e[k] - m[d]) / fmaxf(denom[d], 1e-9f);
    }
}

// ---------------- Kernel 3: agg[n] = sum alpha*h[src]; gfeats = elu(agg)+feats
__global__ __launch_bounds__(256) void agg_kernel(
    const int* __restrict__ edge_index, const float* __restrict__ alpha,
    const float* __restrict__ h, const float* __restrict__ new_emb,
    float* __restrict__ gfeats)
{
    __shared__ float s_alpha[N_EDGES];
    __shared__ int   s_src[N_EDGES];
    __shared__ int   s_dst[N_EDGES];
    const int n = blockIdx.x;
    const int tid = threadIdx.x;

    for (int k = tid; k < N_EDGES; k += 256) {
        s_alpha[k] = alpha[k];
        s_src[k]   = edge_index[k];
        s_dst[k]   = edge_index[N_EDGES + k];
    }
    __syncthreads();

    float a0 = 0.f, a1 = 0.f, a2 = 0.f;
    for (int k = 0; k < N_EDGES; ++k) {
        if (s_dst[k] == n) {
            float a = s_alpha[k];
            const float* hs = h + (size_t)s_src[k] * D;
            a0 = fmaf(a, hs[tid], a0);
            a1 = fmaf(a, hs[tid + 256], a1);
            a2 = fmaf(a, hs[tid + 512], a2);
        }
    }
    const float* f = new_emb + (size_t)(1 + n) * D;
    float e0 = a0 > 0.f ? a0 : expf(a0) - 1.f;
    float e1 = a1 > 0.f ? a1 : expf(a1) - 1.f;
    float e2 = a2 > 0.f ? a2 : expf(a2) - 1.f;
    gfeats[(size_t)n * D + tid]       = e0 + f[tid];
    gfeats[(size_t)n * D + tid + 256] = e1 + f[tid + 256];
    gfeats[(size_t)n * D + tid + 512] = e2 + f[tid + 512];
}

// ---------------- Kernel 4: gather. One wave (64 lanes) per token, 3 float4/lane.
__global__ __launch_bounds__(256) void gather_kernel(
    const int* __restrict__ x, const float* __restrict__ orig_emb,
    const float* __restrict__ gfeats, const float* __restrict__ new_emb,
    float* __restrict__ out, int ntok)
{
    const int token = blockIdx.x * 4 + (threadIdx.x >> 6);
    if (token >= ntok) return;
    const int lane = threadIdx.x & 63;
    const int idx = x[token];

    const float4* src;
    if (idx < VOCAB)
        src = (const float4*)(orig_emb + (size_t)idx * D);
    else if (idx < VOCAB + N_NODES)
        src = (const float4*)(gfeats + (size_t)(idx - VOCAB) * D);
    else
        src = (const float4*)(new_emb + (size_t)N_NEW * D);

    float4* dst = (float4*)(out + (size_t)token * D);
    dst[lane]       = src[lane];
    dst[lane + 64]  = src[lane + 64];
    dst[lane + 128] = src[lane + 128];
}

extern "C" void kernel_launch(void* const* d_in, const int* in_sizes, int n_in,
                              void* d_out, int out_size, void* d_ws, size_t ws_size,
                              hipStream_t stream) {
    const int*   x        = (const int*)  d_in[0];
    const float* orig_emb = (const float*)d_in[1];
    const float* new_emb  = (const float*)d_in[2];
    const float* W        = (const float*)d_in[3];
    const float* a_src    = (const float*)d_in[4];
    const float* a_dst    = (const float*)d_in[5];
    const int*   edge_idx = (const int*)  d_in[6];
    float* out = (float*)d_out;

    // workspace layout (floats)
    float* ws     = (float*)d_ws;
    float* h      = ws;                               // 199*768
    float* sv     = h + (size_t)N_NODES * D;          // 199
    float* dv     = sv + N_NODES;                     // 199
    float* alpha  = dv + N_NODES;                     // 1024
    float* gfeats = alpha + N_EDGES;                  // 199*768

    const int ntok = in_sizes[0];                     // 8*4096 = 32768

    gemm_sd_kernel<<<(N_NODES + ROWS_PB - 1) / ROWS_PB, 256, 0, stream>>>(
        new_emb, W, a_src, a_dst, h, sv, dv);
    softmax_kernel<<<1, 256, 0, stream>>>(edge_idx, sv, dv, alpha);
    agg_kernel<<<N_NODES, 256, 0, stream>>>(edge_idx, alpha, h, new_emb, gfeats);
    gather_kernel<<<(ntok + 3) / 4, 256, 0, stream>>>(
        x, orig_emb, gfeats, new_emb, out, ntok);
}

// Round 2
// 72.223 us; speedup vs baseline: 4.6507x; 4.6507x over previous
//
#include <hip/hip_runtime.h>
#include <math.h>

#define VOCAB   50265
#define D       768
#define N_NEW   200
#define N_NODES 199
#define N_EDGES 1024
#define LEAKY   0.2f

// ---- GEMM split-K config ----
#define ROW_T 4      // rows per block
#define KC    4      // K chunks
#define KLEN  192    // 768 / KC
#define NROWT 50     // ceil(199/4)

// Kernel 1a: partial[kc][row][col] = sum_{k in chunk} feats[row][k] * W[k][col]
__global__ __launch_bounds__(256) void gemm_partial_kernel(
    const float* __restrict__ new_emb, const float* __restrict__ W,
    float* __restrict__ partial)
{
    __shared__ float fts[ROW_T][KLEN];       // 3 KB
    const int tid  = threadIdx.x;
    const int row0 = blockIdx.x * ROW_T;
    const int col  = blockIdx.y * 256 + tid;
    const int k0   = blockIdx.z * KLEN;

    // load 4 rows x 192 k of feats (new_emb rows 1+row0 ..)
    for (int i = tid; i < ROW_T * KLEN; i += 256) {
        int r  = i / KLEN;
        int kk = i - r * KLEN;
        int row = row0 + r;
        fts[r][kk] = (row < N_NODES) ? new_emb[(size_t)(1 + row) * D + k0 + kk] : 0.f;
    }
    __syncthreads();

    float acc0 = 0.f, acc1 = 0.f, acc2 = 0.f, acc3 = 0.f;
    #pragma unroll 4
    for (int kk = 0; kk < KLEN; ++kk) {
        float w = W[(size_t)(k0 + kk) * D + col];
        acc0 = fmaf(fts[0][kk], w, acc0);
        acc1 = fmaf(fts[1][kk], w, acc1);
        acc2 = fmaf(fts[2][kk], w, acc2);
        acc3 = fmaf(fts[3][kk], w, acc3);
    }

    const size_t base = ((size_t)blockIdx.z * N_NODES) * D + col;
    if (row0 + 0 < N_NODES) partial[base + (size_t)(row0 + 0) * D] = acc0;
    if (row0 + 1 < N_NODES) partial[base + (size_t)(row0 + 1) * D] = acc1;
    if (row0 + 2 < N_NODES) partial[base + (size_t)(row0 + 2) * D] = acc2;
    if (row0 + 3 < N_NODES) partial[base + (size_t)(row0 + 3) * D] = acc3;
}

// Kernel 1b: h[row] = sum_kc partial[kc][row]; sv[row]=h.a_src; dv[row]=h.a_dst
__global__ __launch_bounds__(256) void reduce_h_kernel(
    const float* __restrict__ partial, const float* __restrict__ a_src,
    const float* __restrict__ a_dst, float* __restrict__ h,
    float* __restrict__ sv, float* __restrict__ dv)
{
    __shared__ float redS[4], redD[4];
    const int row = blockIdx.x;
    const int tid = threadIdx.x;
    const size_t kcstride = (size_t)N_NODES * D;

    float hv[3];
    #pragma unroll
    for (int j = 0; j < 3; ++j) {
        const size_t idx = (size_t)row * D + tid + j * 256;
        float s = partial[idx];
        s += partial[idx + kcstride];
        s += partial[idx + 2 * kcstride];
        s += partial[idx + 3 * kcstride];
        hv[j] = s;
        h[idx] = s;
    }

    float ps = hv[0] * a_src[tid] + hv[1] * a_src[tid + 256] + hv[2] * a_src[tid + 512];
    float pd = hv[0] * a_dst[tid] + hv[1] * a_dst[tid + 256] + hv[2] * a_dst[tid + 512];
    #pragma unroll
    for (int off = 32; off; off >>= 1) {
        ps += __shfl_down(ps, off, 64);
        pd += __shfl_down(pd, off, 64);
    }
    if ((tid & 63) == 0) { redS[tid >> 6] = ps; redD[tid >> 6] = pd; }
    __syncthreads();
    if (tid == 0) {
        sv[row] = redS[0] + redS[1] + redS[2] + redS[3];
        dv[row] = redD[0] + redD[1] + redD[2] + redD[3];
    }
}

// Kernel 2: edge softmax + CSR build (single block)
__global__ __launch_bounds__(256) void softmax_kernel(
    const int* __restrict__ edge_index, const float* __restrict__ sv,
    const float* __restrict__ dv, float* __restrict__ alpha,
    int* __restrict__ csr_off, int* __restrict__ csr_eid)
{
    __shared__ float e[N_EDGES];
    __shared__ short sdst[N_EDGES];
    __shared__ float m[N_NODES];
    __shared__ float denom[N_NODES];
    __shared__ int   off[N_NODES + 1];
    __shared__ int   cursor[N_NODES];
    __shared__ int   eid[N_EDGES];
    const int tid = threadIdx.x;

    for (int n = tid; n < N_NODES; n += 256) cursor[n] = 0;
    __syncthreads();

    for (int k = tid; k < N_EDGES; k += 256) {
        int s = edge_index[k];
        int d = edge_index[N_EDGES + k];
        sdst[k] = (short)d;
        float ev = sv[s] + dv[d];
        e[k] = ev > 0.f ? ev : LEAKY * ev;
        atomicAdd(&cursor[d], 1);               // counts
    }
    __syncthreads();

    if (tid == 0) {
        int run = 0;
        for (int n = 0; n < N_NODES; ++n) { off[n] = run; run += cursor[n]; }
        off[N_NODES] = run;
    }
    __syncthreads();
    for (int n = tid; n < N_NODES; n += 256) cursor[n] = off[n];
    __syncthreads();

    for (int k = tid; k < N_EDGES; k += 256) {
        int pos = atomicAdd(&cursor[(int)sdst[k]], 1);
        eid[pos] = k;
    }
    __syncthreads();

    // per-node max & denom over its own edges (avg ~5)
    for (int n = tid; n < N_NODES; n += 256) {
        float mx = -INFINITY;
        for (int p = off[n]; p < off[n + 1]; ++p) mx = fmaxf(mx, e[eid[p]]);
        float dn = 0.f;
        for (int p = off[n]; p < off[n + 1]; ++p) dn += expf(e[eid[p]] - mx);
        m[n] = mx;
        denom[n] = dn;
    }
    __syncthreads();

    for (int k = tid; k < N_EDGES; k += 256) {
        int d = (int)sdst[k];
        alpha[k] = expf(e[k] - m[d]) / fmaxf(denom[d], 1e-9f);
    }
    for (int n = tid; n < N_NODES + 1; n += 256) csr_off[n] = off[n];
    for (int k = tid; k < N_EDGES; k += 256)     csr_eid[k] = eid[k];
}

// Kernel 3: agg[n] = sum alpha*h[src] over n's edges; gfeats = elu(agg)+feats
__global__ __launch_bounds__(256) void agg_kernel(
    const int* __restrict__ edge_index, const float* __restrict__ alpha,
    const int* __restrict__ csr_off, const int* __restrict__ csr_eid,
    const float* __restrict__ h, const float* __restrict__ new_emb,
    float* __restrict__ gfeats)
{
    const int n = blockIdx.x;
    const int tid = threadIdx.x;
    const int p0 = csr_off[n], p1 = csr_off[n + 1];

    float a0 = 0.f, a1 = 0.f, a2 = 0.f;
    for (int p = p0; p < p1; ++p) {
        const int k = csr_eid[p];
        const float a = alpha[k];
        const float* hs = h + (size_t)edge_index[k] * D;
        a0 = fmaf(a, hs[tid], a0);
        a1 = fmaf(a, hs[tid + 256], a1);
        a2 = fmaf(a, hs[tid + 512], a2);
    }
    const float* f = new_emb + (size_t)(1 + n) * D;
    float e0 = a0 > 0.f ? a0 : expf(a0) - 1.f;
    float e1 = a1 > 0.f ? a1 : expf(a1) - 1.f;
    float e2 = a2 > 0.f ? a2 : expf(a2) - 1.f;
    gfeats[(size_t)n * D + tid]       = e0 + f[tid];
    gfeats[(size_t)n * D + tid + 256] = e1 + f[tid + 256];
    gfeats[(size_t)n * D + tid + 512] = e2 + f[tid + 512];
}

// Kernel 4: gather. One wave per token, 3 float4/lane.
__global__ __launch_bounds__(256) void gather_kernel(
    const int* __restrict__ x, const float* __restrict__ orig_emb,
    const float* __restrict__ gfeats, const float* __restrict__ new_emb,
    float* __restrict__ out, int ntok)
{
    const int token = blockIdx.x * 4 + (threadIdx.x >> 6);
    if (token >= ntok) return;
    const int lane = threadIdx.x & 63;
    const int idx = x[token];

    const float4* src;
    if (idx < VOCAB)
        src = (const float4*)(orig_emb + (size_t)idx * D);
    else if (idx < VOCAB + N_NODES)
        src = (const float4*)(gfeats + (size_t)(idx - VOCAB) * D);
    else
        src = (const float4*)(new_emb + (size_t)N_NEW * D);

    float4* dst = (float4*)(out + (size_t)token * D);
    dst[lane]       = src[lane];
    dst[lane + 64]  = src[lane + 64];
    dst[lane + 128] = src[lane + 128];
}

extern "C" void kernel_launch(void* const* d_in, const int* in_sizes, int n_in,
                              void* d_out, int out_size, void* d_ws, size_t ws_size,
                              hipStream_t stream) {
    const int*   x        = (const int*)  d_in[0];
    const float* orig_emb = (const float*)d_in[1];
    const float* new_emb  = (const float*)d_in[2];
    const float* W        = (const float*)d_in[3];
    const float* a_src    = (const float*)d_in[4];
    const float* a_dst    = (const float*)d_in[5];
    const int*   edge_idx = (const int*)  d_in[6];
    float* out = (float*)d_out;

    // workspace layout (floats)
    float* ws      = (float*)d_ws;
    float* h       = ws;                               // 199*768
    float* sv      = h + (size_t)N_NODES * D;          // 199
    float* dv      = sv + N_NODES;                     // 199
    float* alpha   = dv + N_NODES;                     // 1024
    float* gfeats  = alpha + N_EDGES;                  // 199*768
    float* partial = gfeats + (size_t)N_NODES * D;     // 4*199*768
    int*   csr_off = (int*)(partial + (size_t)KC * N_NODES * D);  // 200
    int*   csr_eid = csr_off + (N_NODES + 1);                     // 1024

    const int ntok = in_sizes[0];                      // 8*4096 = 32768

    dim3 ggrid(NROWT, 3, KC);
    gemm_partial_kernel<<<ggrid, 256, 0, stream>>>(new_emb, W, partial);
    reduce_h_kernel<<<N_NODES, 256, 0, stream>>>(partial, a_src, a_dst, h, sv, dv);
    softmax_kernel<<<1, 256, 0, stream>>>(edge_idx, sv, dv, alpha, csr_off, csr_eid);
    agg_kernel<<<N_NODES, 256, 0, stream>>>(edge_idx, alpha, csr_off, csr_eid, h, new_emb, gfeats);
    gather_kernel<<<(ntok + 3) / 4, 256, 0, stream>>>(
        x, orig_emb, gfeats, new_emb, out, ntok);
}